// Round 1
// 123.764 us; speedup vs baseline: 1.0120x; 1.0120x over previous
//
#include <hip/hip_runtime.h>
#include <math.h>

// HW exp2 (v_exp_f32) when available.
#if defined(__has_builtin)
#  if __has_builtin(__builtin_amdgcn_exp2f)
#    define EXP2F(x) __builtin_amdgcn_exp2f(x)
#  endif
#endif
#ifndef EXP2F
#  define EXP2F(x) __expf(0.69314718055994530942f * (x))
#endif

// Full-rate-VALU exp2: magic-constant round-to-nearest, deg-3 Taylor on
// f in [-0.5,0.5] (rel err <= 6e-4), exponent rebuilt via (y_int<<23)+p_int.
// Valid for |n| < 512; here arg in [-8, 37]. ~7 full-rate ops, no trans pipe.
__device__ __forceinline__ float fast_exp2(float x) {
  const float M = 12582912.0f;             // 1.5 * 2^23
  const float y = x + M;                   // RNE(x) encoded in mantissa
  const float n = y - M;
  const float f = x - n;                   // [-0.5, 0.5]
  float p = fmaf(f, 0.055504109f, 0.24022651f);
  p = fmaf(f, p, 0.69314718f);
  p = fmaf(f, p, 1.0f);                    // 2^f
  const int r = (__float_as_int(y) << 23) + __float_as_int(p);
  return __int_as_float(r);
}

// One layer of the OR-gate net:
//   aw = leaky_clamp(W, 0, 1, 0.1); z = h*aw
//   out[b,o] = sum_i z * softmax_i(tau*z); hout = 1 - out
// Folding: arg = c2*z, c2 = tau*log2(e); sum z*e = (sum arg*e)/c2.
//
// R4 (this round): stall-attack. Prior evidence: VALUBusy ~26%, no pipe
// saturated (full-rate model floor ~21 us vs 125 us measured) -> latency
// bound, not roofline. Changes:
//  (1) h tile staged in LDS once per block (was 4x-redundant global loads
//      on the latency-critical path every iteration),
//  (2) W stream software-pipelined one full ic ahead in registers,
//  (3) grids rebalanced so every layer has >=4 blocks/CU (L1: BB 4->2,
//      L2: BB 2->1; extra W re-reads are L2-resident, ~6% of L2 BW),
//  (4) __launch_bounds__(256,4) pins 4 waves/SIMD.
template <int IN, int OUT, int BB, bool FIRST>
__launch_bounds__(256, 4)
__global__ void or_layer(const float* __restrict__ hin,
                         const float* __restrict__ W,
                         const float* __restrict__ tau_ptr,
                         float* __restrict__ hout,
                         float tau_floor) {
  constexpr int OBB = 2;                 // outputs per 16-lane group
  constexpr int NIT = IN / 64;           // 16 lanes x float4 per iter
  constexpr int nOT = OUT / 32;          // 4 waves x 8 outputs per block
  constexpr int IN4 = IN / 4;            // row length in float4

  __shared__ float4 lds_h[BB][IN4];      // 16KB (L0/..) down to 1KB (L3)

  const int tid  = threadIdx.x;
  const int lane = tid & 63;
  const int wid  = tid >> 6;
  const int il   = lane & 15;            // i-lane within group
  const int og   = lane >> 4;            // o-group 0..3

  const int ot = blockIdx.x % nOT;
  const int bt = blockIdx.x / nOT;
  const int b0 = bt * BB;
  const int o0 = ot * 32 + wid * 8 + og * OBB;

  const float ta  = tau_ptr[0];
  const float tau = tau_floor + (ta >= 0.0f ? ta : 0.05f * ta);
  const float c2  = tau * 1.44269504088896340736f;  // tau * log2(e)

  const float4* __restrict__ Wv = (const float4*)W;
  const float4* __restrict__ Hv = (const float4*)hin;

  // ---- stage h tile into LDS (once per block; reused by all NIT iters
  //      and all 4 o-groups per wave) ----
  if (FIRST) {
    // hin is x: (128, IN/2); h = concat(x, 1-x).
    constexpr int HALF4 = IN / 8;
    for (int idx = tid; idx < BB * HALF4; idx += 256) {
      const int r = idx / HALF4;
      const int k = idx - r * HALF4;
      const float4 v = Hv[(b0 + r) * HALF4 + k];
      lds_h[r][k] = v;
      lds_h[r][HALF4 + k] =
          make_float4(1.0f - v.x, 1.0f - v.y, 1.0f - v.z, 1.0f - v.w);
    }
  } else {
    for (int idx = tid; idx < BB * IN4; idx += 256) {
      const int r = idx / IN4;
      const int k = idx - r * IN4;
      lds_h[r][k] = Hv[(b0 + r) * IN4 + k];
    }
  }
  __syncthreads();

  float s[BB][OBB], t[BB][OBB];
#pragma unroll
  for (int r = 0; r < BB; ++r)
#pragma unroll
    for (int c = 0; c < OBB; ++c) { s[r][c] = 0.0f; t[r][c] = 0.0f; }

  // W stream: software pipeline, prefetch distance = 1 full ic iteration
  // (~600 issue-cycles of compute between load issue and first use).
  const float4* wp0 = Wv + (size_t)(o0 + 0) * IN4 + il;
  const float4* wp1 = Wv + (size_t)(o0 + 1) * IN4 + il;

  float4 wcur0 = wp0[0];
  float4 wcur1 = wp1[0];

#pragma unroll 2
  for (int ic = 0; ic < NIT; ++ic) {
    const int icn = (ic + 1 < NIT) ? (ic + 1) : (NIT - 1);  // keep loads unconditional
    const float4 wnxt0 = wp0[icn * 16];
    const float4 wnxt1 = wp1[icn * 16];

    // h from LDS: broadcast across the 4 o-groups, 2-way banked -> free.
    float hc[BB][4];
#pragma unroll
    for (int r = 0; r < BB; ++r) {
      const float4 v = lds_h[r][ic * 16 + il];
      hc[r][0] = v.x; hc[r][1] = v.y; hc[r][2] = v.z; hc[r][3] = v.w;
    }

    float cw[OBB][4];
    {
      const float wj0[4] = {wcur0.x, wcur0.y, wcur0.z, wcur0.w};
      const float wj1[4] = {wcur1.x, wcur1.y, wcur1.z, wcur1.w};
#pragma unroll
      for (int j = 0; j < 4; ++j) {
        float m  = fminf(fmaxf(wj0[j], 0.0f), 1.0f);        // med3 clamp
        cw[0][j] = c2 * fmaf(0.1f, wj0[j] - m, m);          // leaky outside
        m        = fminf(fmaxf(wj1[j], 0.0f), 1.0f);
        cw[1][j] = c2 * fmaf(0.1f, wj1[j] - m, m);
      }
    }

#pragma unroll
    for (int r = 0; r < BB; ++r)
#pragma unroll
      for (int c = 0; c < OBB; ++c)
#pragma unroll
        for (int j = 0; j < 4; ++j) {
          const float arg = cw[c][j] * hc[r][j];
          // Hybrid: even j on the trans pipe, odd j on the full-rate pipe.
          const float e = (j & 1) ? fast_exp2(arg) : EXP2F(arg);
          s[r][c] += e;
          t[r][c]  = fmaf(arg, e, t[r][c]);
        }

    wcur0 = wnxt0;
    wcur1 = wnxt1;
  }

  // Reduce partials across the 16 i-lanes of each group.
#pragma unroll
  for (int m = 1; m < 16; m <<= 1)
#pragma unroll
    for (int r = 0; r < BB; ++r)
#pragma unroll
      for (int c = 0; c < OBB; ++c) {
        s[r][c] += __shfl_xor(s[r][c], m, 64);
        t[r][c] += __shfl_xor(t[r][c], m, 64);
      }

  if (il == 0) {
    const float inv_c2 = 1.0f / c2;
#pragma unroll
    for (int r = 0; r < BB; ++r)
#pragma unroll
      for (int c = 0; c < OBB; ++c) {
        const float out = t[r][c] / s[r][c] * inv_c2;  // sum(z e)/sum(e)
        hout[(b0 + r) * OUT + (o0 + c)] = 1.0f - out;
      }
  }
}

extern "C" void kernel_launch(void* const* d_in, const int* in_sizes, int n_in,
                              void* d_out, int out_size, void* d_ws, size_t ws_size,
                              hipStream_t stream) {
  // setup_inputs() dict order: x, W0, tau0, W1, tau1, W2, tau2, W3, tau3
  const float* x    = (const float*)d_in[0];
  const float* W0   = (const float*)d_in[1];
  const float* tau0 = (const float*)d_in[2];
  const float* W1   = (const float*)d_in[3];
  const float* tau1 = (const float*)d_in[4];
  const float* W2   = (const float*)d_in[5];
  const float* tau2 = (const float*)d_in[6];
  const float* W3   = (const float*)d_in[7];
  const float* tau3 = (const float*)d_in[8];

  float* h1  = (float*)d_ws;        // 128*1024 floats
  float* h2  = h1 + 128 * 1024;     // 128*512
  float* h3  = h2 + 128 * 512;      // 128*256
  float* out = (float*)d_out;       // 128*128

  const double LOGR = 2.9444389791664403;  // log(0.95) - log(0.05) = log(19)
  const float tf1024 = (float)(log(1023.0) + LOGR);
  const float tf512  = (float)(log(511.0)  + LOGR);
  const float tf256  = (float)(log(255.0)  + LOGR);

  // Grid = (OUT/32) * (128/BB). All layers now >= 4 blocks/CU except L3.
  or_layer<1024, 1024, 4, true ><<<1024, 256, 0, stream>>>(x,  W0, tau0, h1,  tf1024);
  or_layer<1024,  512, 2, false><<<1024, 256, 0, stream>>>(h1, W1, tau1, h2,  tf1024);
  or_layer< 512,  256, 1, false><<<1024, 256, 0, stream>>>(h2, W2, tau2, h3,  tf512);
  or_layer< 256,  128, 1, false><<< 512, 256, 0, stream>>>(h3, W3, tau3, out, tf256);
}